// Round 16
// baseline (27.000 us; speedup 1.0000x reference)
//
#include <hip/hip_runtime.h>
#include <math.h>

typedef short bf16x8 __attribute__((ext_vector_type(8)));
typedef float f32x4 __attribute__((ext_vector_type(4)));
typedef unsigned short u16;
typedef unsigned int u32;

// ws byte offsets: QT (B,N,32) bf16, KT (B,N,32) bf16,
// VW (B,32,1032) bf16 (1024 + 8 pad per kd row, pad zeroed by proj),
// QXY (B,N,2) f32, KXY (B,N,2) f32
#define WS_QT  0
#define WS_KT  1048576
#define WS_VW  2097152
#define WS_QXY 3153920
#define WS_KXY 3284992
#define VWS    1032

__device__ __forceinline__ u32 f2bf(float f) {
    u32 u = __float_as_uint(f);
    u += 0x7fffu + ((u >> 16) & 1u);
    return u >> 16;
}
__device__ __forceinline__ u32 pk2(float a, float b) {
    return f2bf(a) | (f2bf(b) << 16);
}

union U4H { uint4 u; bf16x8 h; };

// ---------- projections as MFMA GEMM: 2048 one-wave blocks (round-15 verbatim) ----
__global__ __launch_bounds__(64) void proj_kernel(
    const float* __restrict__ x,
    const float* __restrict__ Wq, const float* __restrict__ Wk,
    const float* __restrict__ Wv, const float* __restrict__ Wqxy,
    const float* __restrict__ Wkxy, char* __restrict__ wsb)
{
    u16* QT = (u16*)(wsb + WS_QT);
    u16* KT = (u16*)(wsb + WS_KT);
    u16* VW = (u16*)(wsb + WS_VW);
    float* QXY = (float*)(wsb + WS_QXY);
    float* KXY = (float*)(wsb + WS_KXY);

    int l = threadIdx.x;
    int g = l >> 4, l15 = l & 15;
    int bid = blockIdx.x;
    int xcd = bid & 7, j = bid >> 3;             // bijective XCD swizzle
    int b = (xcd << 1) + (j >> 7);               // 2 batches per XCD
    int h = j & 1;                               // j-tile half
    int n0 = ((j >> 1) & 63) << 4;

    bf16x8 ah[2], al[2];
    #pragma unroll
    for (int ks = 0; ks < 2; ks++) {
        float av[8];
        #pragma unroll
        for (int i = 0; i < 8; i++)
            av[i] = x[(((b << 6) + (ks << 5) + (g << 3) + i) << 10) + n0 + l15];
        #pragma unroll
        for (int i = 0; i < 8; i++) {
            u32 hb = f2bf(av[i]);
            float rr = av[i] - __uint_as_float(hb << 16);
            ah[ks][i] = (short)hb;
            al[ks][i] = (short)f2bf(rr);
        }
    }

    auto do_jt = [&](int jt) {
        f32x4 acc = {0.f, 0.f, 0.f, 0.f};
        #pragma unroll
        for (int ks = 0; ks < 2; ks++) {
            float wv[8];
            #pragma unroll
            for (int i = 0; i < 8; i++) wv[i] = 0.f;
            if (jt < 6) {
                const float* wbase = (jt < 2) ? Wq : (jt < 4) ? Wk : Wv;
                const float* wr = wbase + ((((jt & 1) << 4) + l15) << 6)
                                        + (ks << 5) + (g << 3);
                float4 wa = *(const float4*)wr, wb = *(const float4*)(wr + 4);
                wv[0] = wa.x; wv[1] = wa.y; wv[2] = wa.z; wv[3] = wa.w;
                wv[4] = wb.x; wv[5] = wb.y; wv[6] = wb.z; wv[7] = wb.w;
            } else if (l15 < 4) {
                const float* wr = ((l15 < 2) ? (Wqxy + (l15 << 6))
                                             : (Wkxy + ((l15 - 2) << 6)))
                                  + (ks << 5) + (g << 3);
                float4 wa = *(const float4*)wr, wb = *(const float4*)(wr + 4);
                wv[0] = wa.x; wv[1] = wa.y; wv[2] = wa.z; wv[3] = wa.w;
                wv[4] = wb.x; wv[5] = wb.y; wv[6] = wb.z; wv[7] = wb.w;
            }
            bf16x8 wh, wl;
            #pragma unroll
            for (int i = 0; i < 8; i++) {
                u32 hb = f2bf(wv[i]);
                float rr = wv[i] - __uint_as_float(hb << 16);
                wh[i] = (short)hb;
                wl[i] = (short)f2bf(rr);
            }
            acc = __builtin_amdgcn_mfma_f32_16x16x32_bf16(ah[ks], wh, acc, 0, 0, 0);
            acc = __builtin_amdgcn_mfma_f32_16x16x32_bf16(al[ks], wh, acc, 0, 0, 0);
            acc = __builtin_amdgcn_mfma_f32_16x16x32_bf16(ah[ks], wl, acc, 0, 0, 0);
        }
        if (jt < 2) {
            #pragma unroll
            for (int r = 0; r < 4; r++)
                QT[(((b << 10) + n0 + (g << 2) + r) << 5) + (jt << 4) + l15]
                    = (u16)f2bf(acc[r]);
        } else if (jt < 4) {
            #pragma unroll
            for (int r = 0; r < 4; r++)
                KT[(((b << 10) + n0 + (g << 2) + r) << 5) + ((jt - 2) << 4) + l15]
                    = (u16)f2bf(acc[r]);
        } else if (jt < 6) {
            int kd = ((jt - 4) << 4) + l15;
            uint2 d = make_uint2(pk2(acc[0], acc[1]), pk2(acc[2], acc[3]));
            *(uint2*)&VW[((b << 5) + kd) * VWS + n0 + (g << 2)] = d;
        } else {
            if (l15 < 2) {
                #pragma unroll
                for (int r = 0; r < 4; r++)
                    QXY[(((b << 10) + n0 + (g << 2) + r) << 1) + l15] = acc[r];
            } else if (l15 < 4) {
                #pragma unroll
                for (int r = 0; r < 4; r++)
                    KXY[(((b << 10) + n0 + (g << 2) + r) << 1) + (l15 - 2)] = acc[r];
            }
        }
    };

    if (h == 0) {
        #pragma unroll
        for (int jt = 0; jt < 4; jt++) do_jt(jt);
    } else {
        #pragma unroll
        for (int jt = 4; jt < 7; jt++) do_jt(jt);
        if (((j >> 1) & 63) == 63 && l < 32)
            *(uint4*)&VW[((b << 5) + l) * VWS + 1024] = make_uint4(0, 0, 0, 0);
    }
}

// ---------- attention: 2048 single-wave blocks = (b, 4x2-query tile) ----------
// Wave = 8 queries (MFMA cols 8-15 duplicate 0-7), region 16 rows x 16 cols
// (rx0 = qx0-7). K and V read DIRECTLY from global (XCD-L2-local); no
// barriers at all (LDS is wave-private: kxy 2KB + o_l 1KB). 8 blocks/CU =
// 2 waves/SIMD. xy-scores computed exactly in fp32 on the VALU and added to
// the QK accumulator. PV k-blocks = row pairs, identical A/B k-maps.
// C/D (HW-verified): col=lane&15, row=(lane>>4)*4+reg.
__global__ __launch_bounds__(64) void attn_kernel(
    const char* __restrict__ wsb, const float* __restrict__ Wout,
    float* __restrict__ out)
{
    const u16* QT = (const u16*)(wsb + WS_QT);
    const u16* KT = (const u16*)(wsb + WS_KT);
    const u16* VW = (const u16*)(wsb + WS_VW);
    const float* QXY = (const float*)(wsb + WS_QXY);
    const float* KXY = (const float*)(wsb + WS_KXY);

    __shared__ __align__(16) float kxy_l[256 * 2];   // region slot xy, f32
    __shared__ __align__(16) u16 o_l[8 * 32];        // O transpose (8 q x 32 kd)

    int lane = threadIdx.x, bid = blockIdx.x;
    int xcd = bid & 7, j = bid >> 3;             // bijective XCD swizzle
    int b = (xcd << 1) + (j >> 7);
    int tile = j & 127;
    int qy0 = (tile >> 4) << 2, qx0 = (tile & 15) << 1;
    int ry0 = qy0 - 6, rx0 = qx0 - 7;

    int g = lane >> 4, lq = lane & 15;
    int q8 = lq & 7;                             // real query id (8-15 dup 0-7)
    int qrl = q8 >> 1, qcol = q8 & 1;
    int nq = (qy0 + qrl) * 32 + qx0 + qcol;

    // ---- stage kxy (wave-private, no barrier; lane loads 4 slots)
    #pragma unroll
    for (int i = 0; i < 4; i++) {
        int s = (lane << 2) + i;
        int n2 = (ry0 + (s >> 4)) * 32 + rx0 + (s & 15);
        n2 = max(0, min(1023, n2));
        *(float2*)&kxy_l[s << 1] = *(const float2*)(KXY + (((b << 10) + n2) << 1));
    }

    // ---- per-lane query data
    U4H bq; bq.u = *(const uint4*)(QT + (((b << 10) + nq) << 5) + (g << 3));
    float2 qv = *(const float2*)(QXY + (((b << 10) + nq) << 1));

    // ---- QK^T (swapped; K direct from global) + exact fp32 xy add
    // acc[t][r] = S[region col 4g+r, region row t][q=lq]
    f32x4 acc[16];
    #pragma unroll
    for (int t = 0; t < 16; t++) {
        int n2 = (ry0 + t) * 32 + rx0 + lq;
        n2 = max(0, min(1023, n2));
        U4H ak; ak.u = *(const uint4*)(KT + (((b << 10) + n2) << 5) + (g << 3));
        f32x4 z = {0.f, 0.f, 0.f, 0.f};
        acc[t] = __builtin_amdgcn_mfma_f32_16x16x32_bf16(ak.h, bq.h, z, 0, 0, 0);
    }
    #pragma unroll
    for (int t = 0; t < 16; t++) {
        #pragma unroll
        for (int r = 0; r < 4; r++) {
            float2 k2 = *(float2*)&kxy_l[((t << 4) + (g << 2) + r) << 1];
            acc[t][r] += qv.x * k2.x + qv.y * k2.y;
        }
    }

    // ---- mask + softmax (per-lane partials + cross-g combine, 4 shuffles)
    int dx2a[4], kxa[4];
    #pragma unroll
    for (int r = 0; r < 4; r++) {
        int sc = (g << 2) + r;
        int kx = rx0 + sc;
        kxa[r] = (kx >= 0) && (kx < 32);
        int dx = sc - 7 - qcol;
        dx2a[r] = dx * dx;
    }
    float m = -1e30f;
    #pragma unroll
    for (int t = 0; t < 16; t++) {
        int ky = ry0 + t;
        bool kyok = (ky >= 0) && (ky < 32);
        int dy = t - 6 - qrl, dy2 = dy * dy;
        #pragma unroll
        for (int r = 0; r < 4; r++) {
            bool ok = kyok && kxa[r] && (dy2 + dx2a[r] <= 36);
            acc[t][r] = ok ? acc[t][r] : -1e4f;
            m = fmaxf(m, acc[t][r]);
        }
    }
    m = fmaxf(m, __shfl_xor(m, 16, 64));
    m = fmaxf(m, __shfl_xor(m, 32, 64));

    float sum = 0.f;
    #pragma unroll
    for (int t = 0; t < 16; t++) {
        #pragma unroll
        for (int r = 0; r < 4; r++) {
            float e = __expf(acc[t][r] - m);
            acc[t][r] = e;
            sum += e;
        }
    }
    sum += __shfl_xor(sum, 16, 64);
    sum += __shfl_xor(sum, 32, 64);

    float rinv = 1.f / sum;
    #pragma unroll
    for (int t = 0; t < 16; t++) {
        #pragma unroll
        for (int r = 0; r < 4; r++) acc[t][r] *= rinv;   // pre-scale P (linear)
    }

    // ---- PV: k-block kk = rows (2kk,2kk+1) x cols (4g..4g+3); V direct.
    // A k-map i=4p+c matches B granule order (row-major uint2 pairs).
    f32x4 o0 = {0.f, 0.f, 0.f, 0.f}, o1 = {0.f, 0.f, 0.f, 0.f};
    #pragma unroll
    for (int kk = 0; kk < 8; kk++) {
        U4H pa;
        pa.u = make_uint4(pk2(acc[2 * kk][0],     acc[2 * kk][1]),
                          pk2(acc[2 * kk][2],     acc[2 * kk][3]),
                          pk2(acc[2 * kk + 1][0], acc[2 * kk + 1][1]),
                          pk2(acc[2 * kk + 1][2], acc[2 * kk + 1][3]));
        int ky0a = ry0 + (kk << 1), ky1a = ky0a + 1;
        int na = ((u32)ky0a > 31u) ? 0 : (ky0a * 32 + rx0 + (g << 2));
        int nb = ((u32)ky1a > 31u) ? 0 : (ky1a * 32 + rx0 + (g << 2));
        const u16* v0b = VW + ((b << 5) + lq) * VWS;
        const u16* v1b = VW + ((b << 5) + lq + 16) * VWS;
        uint2 a0 = *(const uint2*)(v0b + na), a1 = *(const uint2*)(v0b + nb);
        uint2 b0 = *(const uint2*)(v1b + na), b1 = *(const uint2*)(v1b + nb);
        U4H v0; v0.u = make_uint4(a0.x, a0.y, a1.x, a1.y);
        U4H v1; v1.u = make_uint4(b0.x, b0.y, b1.x, b1.y);
        o0 = __builtin_amdgcn_mfma_f32_16x16x32_bf16(pa.h, v0.h, o0, 0, 0, 0);
        o1 = __builtin_amdgcn_mfma_f32_16x16x32_bf16(pa.h, v1.h, o1, 0, 0, 0);
    }

    // ---- O transpose via wave-private LDS (g<2 rows are the 8 real queries)
    if (g < 2) {
        #pragma unroll
        for (int r = 0; r < 4; r++) {
            int q = (g << 2) + r;
            o_l[(q << 5) + lq]      = (u16)f2bf(o0[r]);
            o_l[(q << 5) + lq + 16] = (u16)f2bf(o1[r]);
        }
    }

    // ---- epilogue: Y = O * Wout^T (Wout frags direct from global)
    U4H aO; aO.u = *(const uint4*)&o_l[(q8 << 5) + (g << 3)];
    #pragma unroll
    for (int nt = 0; nt < 4; nt++) {
        int cc = (nt << 4) + lq;
        const float* wsrc = Wout + (cc << 5) + (g << 3);
        U4H bw;
        bw.u.x = pk2(wsrc[0], wsrc[1]); bw.u.y = pk2(wsrc[2], wsrc[3]);
        bw.u.z = pk2(wsrc[4], wsrc[5]); bw.u.w = pk2(wsrc[6], wsrc[7]);
        f32x4 z = {0.f, 0.f, 0.f, 0.f};
        f32x4 y = __builtin_amdgcn_mfma_f32_16x16x32_bf16(aO.h, bw.h, z, 0, 0, 0);
        if (g < 2) {
            #pragma unroll
            for (int r = 0; r < 4; r++) {
                int q = (g << 2) + r;
                int nqo = (qy0 + (q >> 1)) * 32 + qx0 + (q & 1);
                out[(((b << 6) + cc) << 10) + nqo] = y[r];
            }
        }
    }
}

extern "C" void kernel_launch(void* const* d_in, const int* in_sizes, int n_in,
                              void* d_out, int out_size, void* d_ws, size_t ws_size,
                              hipStream_t stream) {
    const float* x    = (const float*)d_in[0];
    const float* Wq   = (const float*)d_in[1];
    const float* Wk   = (const float*)d_in[2];
    const float* Wv   = (const float*)d_in[3];
    const float* Wqxy = (const float*)d_in[4];
    const float* Wkxy = (const float*)d_in[5];
    const float* Wout = (const float*)d_in[6];
    float* out = (float*)d_out;
    char* wsb  = (char*)d_ws;

    proj_kernel<<<2048, 64, 0, stream>>>(x, Wq, Wk, Wv, Wqxy, Wkxy, wsb);
    attn_kernel<<<2048, 64, 0, stream>>>(wsb, Wout, out);
}